// Round 9
// baseline (790.177 us; speedup 1.0000x reference)
//
#include <hip/hip_runtime.h>
#include <math.h>

#define NPG 256
#define EPG 4096
#define NG  512
#define FIN 128
#define HD  64
#define TOUT 18
#define KTOP 16
#define STA 68                    // h row stride (floats)
#define SRCL_CAP (EPG + 3*NPG)
#define E_TOT (NG*EPG)

__device__ __forceinline__ float dot4(float4 a, float4 b) {
    return a.x*b.x + a.y*b.y + a.z*b.z + a.w*b.w;
}

__launch_bounds__(512, 4)         // 8-wave block, 2 blocks/CU, VGPR cap 128
__global__ void dgcnn_fused(
    const float* __restrict__ x,
    const int*   __restrict__ ei,
    const float* __restrict__ w0, const float* __restrict__ b0,
    const float* __restrict__ w1, const float* __restrict__ b1,
    const float* __restrict__ w2, const float* __restrict__ b2,
    const float* __restrict__ w3, const float* __restrict__ b3,
    const float* __restrict__ w4, const float* __restrict__ b4,
    const float* __restrict__ c1w, const float* __restrict__ c1b,
    const float* __restrict__ c2w, const float* __restrict__ c2b,
    const float* __restrict__ d1w, const float* __restrict__ d1b,
    const float* __restrict__ d2w, const float* __restrict__ d2b,
    float* __restrict__ out)
{
    __shared__ __align__(16) float s_h[NPG*STA];   // h_lin / h / proj+head (aliased)
    __shared__ unsigned char s_srcl[SRCL_CAP] __attribute__((aligned(4)));
    __shared__ int   s_off[NPG+1];
    __shared__ int   s_cnt[NPG];
    __shared__ float s_invdeg[NPG];
    __shared__ float s_lin5[NPG];
    __shared__ float s_h5[NPG];
    __shared__ int   s_sel[KTOP];
    int*   s_cur   = (int*)s_h;            // phase-0 alias
    int*   s_outd  = ((int*)s_h) + NPG;    // phase-0 alias
    float* s_proj  = s_h;                  // final alias: [256][20] proj rows
    float* s_headf = s_h + 8192;           // head scratch

    const int g    = blockIdx.x;
    const int t    = threadIdx.x;
    const int lane = t & 63;
    const int wid  = t >> 6;                        // 0..7
    const int n    = t & 255;                       // owned node
    const int hf   = t >> 8;                        // 0..1 channel half
    const int c32  = __builtin_amdgcn_readfirstlane(hf * 32);
    const int o8   = __builtin_amdgcn_readfirstlane(hf * 8);
    const int js   = lane >> 4;
    const int q4   = (lane & 15) << 2;
    const int gbase = g * NPG;
    const int* __restrict__ srcg = ei + (size_t)g * EPG;
    const int* __restrict__ dstg = ei + (size_t)E_TOT + (size_t)g * EPG;

    // ---------------- phase 0: degrees + 4-padded CSR (by dst) ----------------
    if (t < NPG) { s_cnt[t] = 0; s_outd[t] = 0; }
    __syncthreads();
    for (int e = t; e < EPG; e += 512) {
        int s = srcg[e] - gbase, d = dstg[e] - gbase;
        atomicAdd(&s_outd[s], 1);
        atomicAdd(&s_cnt[d], 1);
    }
    __syncthreads();
    if (t < NPG) s_invdeg[t] = __fdividef(1.0f, (float)(s_outd[t] + 1));
    if (wid == 0) {
        int p4 = lane * 4;
        int c0_ = s_cnt[p4], c1_ = s_cnt[p4+1], c2_ = s_cnt[p4+2], c3_ = s_cnt[p4+3];
        int q0 = (c0_+3)&~3, q1 = (c1_+3)&~3, q2 = (c2_+3)&~3, q3 = (c3_+3)&~3;
        int tot = q0+q1+q2+q3;
        int run = tot;
        #pragma unroll
        for (int o = 1; o < 64; o <<= 1) {
            int v = __shfl_up(run, o);
            if (lane >= o) run += v;
        }
        int base = run - tot;
        s_off[p4]   = base;
        s_off[p4+1] = base + q0;
        s_off[p4+2] = base + q0 + q1;
        s_off[p4+3] = base + q0 + q1 + q2;
        if (lane == 63) s_off[NPG] = run;
    }
    __syncthreads();
    if (t < NPG) s_cur[t] = s_off[t];
    __syncthreads();
    for (int e = t; e < EPG; e += 512) {
        int s = srcg[e] - gbase, d = dstg[e] - gbase;
        int pos = atomicAdd(&s_cur[d], 1);
        s_srcl[pos] = (unsigned char)s;
    }
    __syncthreads();
    if (t < NPG) {                                   // pad to x4 with sentinel src=t
        int pe = s_off[t+1];
        for (int p = s_cur[t]; p < pe; p++) s_srcl[p] = (unsigned char)t;
    }
    __syncthreads();                                 // CSR done; s_h aliases dead

    float proj[8] = {0.f,0.f,0.f,0.f,0.f,0.f,0.f,0.f};

    // agg (in place): h[d] = tanh(invdeg*(sum_src hl[src] + hl[d]))
    auto aggregate = [&]() {
        float4 res[8];
        #pragma unroll
        for (int r = 0; r < 8; r++) {
            int d = (wid + 8*r)*4 + js;
            int off = s_off[d], pe = s_off[d+1];
            int npad = (pe - off) - s_cnt[d];
            float4 a = *(const float4*)&s_h[d*STA + q4];
            float cf = (float)(1 - npad);
            a.x *= cf; a.y *= cf; a.z *= cf; a.w *= cf;
            for (int e = off; e < pe; e += 4) {
                unsigned sq = *(const unsigned*)&s_srcl[e];
                #pragma unroll
                for (int m = 0; m < 4; m++) {
                    int src = (sq >> (8*m)) & 255;
                    float4 hv = *(const float4*)&s_h[src*STA + q4];
                    a.x += hv.x; a.y += hv.y; a.z += hv.z; a.w += hv.w;
                }
            }
            float id = s_invdeg[d];
            res[r].x = tanhf(a.x * id); res[r].y = tanhf(a.y * id);
            res[r].z = tanhf(a.z * id); res[r].w = tanhf(a.w * id);
        }
        __syncthreads();                             // all reads of h_lin complete
        #pragma unroll
        for (int r = 0; r < 8; r++) {
            int d = (wid + 8*r)*4 + js;
            *(float4*)&s_h[d*STA + q4] = res[r];
        }
        __syncthreads();
    };

    // hidden matmul (64->64) + folded conv1-proj slice; row in regs, uniform s_load
    // ALL loops indexing register arrays are FULLY unrolled (static indices).
    auto mmHidden = [&](const float* __restrict__ w, const float* __restrict__ b,
                        const float* __restrict__ c1s) {
        float acc[32];
        #pragma unroll
        for (int j = 0; j < 32; j++) acc[j] = b[c32 + j];
        #pragma unroll
        for (int kh = 0; kh < 2; kh++) {
            float4 row[8];
            #pragma unroll
            for (int q = 0; q < 8; q++)
                row[q] = *(const float4*)&s_h[n*STA + kh*32 + q*4];
            #pragma unroll
            for (int j = 0; j < 32; j++) {
                const float4* wr = (const float4*)(w + (c32+j)*HD + kh*32);
                float s = 0.f;
                #pragma unroll
                for (int q = 0; q < 8; q++) s += dot4(row[q], wr[q]);
                acc[j] += s;
            }
            #pragma unroll
            for (int p = 0; p < 8; p++) {
                const float* cr = c1s + (o8+p)*257 + kh*32;
                float s = 0.f;
                #pragma unroll
                for (int q = 0; q < 8; q++)
                    s += row[q].x*cr[4*q] + row[q].y*cr[4*q+1]
                       + row[q].z*cr[4*q+2] + row[q].w*cr[4*q+3];
                proj[p] += s;
            }
        }
        __syncthreads();                             // all row reads complete
        #pragma unroll
        for (int j4 = 0; j4 < 8; j4++) {
            float4 v = {acc[4*j4], acc[4*j4+1], acc[4*j4+2], acc[4*j4+3]};
            *(float4*)&s_h[n*STA + c32 + 4*j4] = v;
        }
        __syncthreads();
    };

    // ---------------- layer 0 (F=128; x rows read directly from global) -------
    {
        float acc[32];
        #pragma unroll
        for (int j = 0; j < 32; j++) acc[j] = b0[c32 + j];
        const float* xr = x + (size_t)(gbase + n) * FIN;
        #pragma unroll
        for (int kh = 0; kh < 4; kh++) {
            float4 row[8];
            #pragma unroll
            for (int q = 0; q < 8; q++)
                row[q] = *(const float4*)&xr[kh*32 + q*4];
            #pragma unroll
            for (int j = 0; j < 32; j++) {
                const float4* wr = (const float4*)(w0 + (c32+j)*FIN + kh*32);
                float s = 0.f;
                #pragma unroll
                for (int q = 0; q < 8; q++) s += dot4(row[q], wr[q]);
                acc[j] += s;
            }
        }
        #pragma unroll
        for (int j4 = 0; j4 < 8; j4++) {
            float4 v = {acc[4*j4], acc[4*j4+1], acc[4*j4+2], acc[4*j4+3]};
            *(float4*)&s_h[n*STA + c32 + 4*j4] = v;
        }
        __syncthreads();
    }
    aggregate();                                     // -> h0

    mmHidden(w1, b1, c1w);                           // h0 -> hl1, proj slice 0
    aggregate();                                     // -> h1
    mmHidden(w2, b2, c1w + 64);                      // h1 -> hl2, proj slice 64
    aggregate();                                     // -> h2
    mmHidden(w3, b3, c1w + 128);                     // h2 -> hl3, proj slice 128
    aggregate();                                     // -> h3

    // ---------------- layer 4 (64->1) + proj slice 192 -----------------------
    {
        float l5 = 0.f;
        #pragma unroll
        for (int kh = 0; kh < 2; kh++) {
            float4 row[8];
            #pragma unroll
            for (int q = 0; q < 8; q++)
                row[q] = *(const float4*)&s_h[n*STA + kh*32 + q*4];
            #pragma unroll
            for (int p = 0; p < 8; p++) {
                const float* cr = c1w + (o8+p)*257 + 192 + kh*32;
                float s = 0.f;
                #pragma unroll
                for (int q = 0; q < 8; q++)
                    s += row[q].x*cr[4*q] + row[q].y*cr[4*q+1]
                       + row[q].z*cr[4*q+2] + row[q].w*cr[4*q+3];
                proj[p] += s;
            }
            if (hf == 0) {
                #pragma unroll
                for (int q = 0; q < 8; q++)
                    l5 += dot4(row[q], *(const float4*)&w4[kh*32 + q*4]);
            }
        }
        if (hf == 0) s_lin5[n] = l5 + b4[0];
        __syncthreads();                             // h3 reads done; lin5 ready
        if (t < NPG) {
            int d = t;
            int off = s_off[d], pe = s_off[d+1];
            int npad = (pe - off) - s_cnt[d];
            float a = (float)(1 - npad) * s_lin5[d];
            for (int e = off; e < pe; e += 4) {
                unsigned sq = *(const unsigned*)&s_srcl[e];
                a += s_lin5[sq & 255] + s_lin5[(sq>>8)&255]
                   + s_lin5[(sq>>16)&255] + s_lin5[(sq>>24)&255];
            }
            s_h5[d] = tanhf(a * s_invdeg[d]);
        }
        __syncthreads();
        {   // finalize proj with h5 term; store proj rows (s_h alias safe now)
            float h5v = s_h5[n];
            #pragma unroll
            for (int p = 0; p < 8; p++) proj[p] += h5v * c1w[(o8+p)*257 + 256];
            float4 v0 = {proj[0], proj[1], proj[2], proj[3]};
            float4 v1 = {proj[4], proj[5], proj[6], proj[7]};
            *(float4*)&s_proj[n*20 + o8]     = v0;
            *(float4*)&s_proj[n*20 + o8 + 4] = v1;
        }
        if (wid == 0) {                              // top-16: desc value, asc index ties
            float v[4]; int idx[4];
            int p4 = lane * 4;
            #pragma unroll
            for (int j = 0; j < 4; j++) { idx[j] = p4 + j; v[j] = s_h5[p4 + j]; }
            for (int r = 0; r < KTOP; r++) {
                float bv = v[0]; int bi = idx[0];
                #pragma unroll
                for (int j = 1; j < 4; j++)
                    if (v[j] > bv || (v[j] == bv && idx[j] < bi)) { bv = v[j]; bi = idx[j]; }
                #pragma unroll
                for (int o = 32; o > 0; o >>= 1) {
                    float ov = __shfl_xor(bv, o);
                    int   oi = __shfl_xor(bi, o);
                    if (ov > bv || (ov == bv && oi < bi)) { bv = ov; bi = oi; }
                }
                if ((bi >> 2) == lane) v[bi & 3] = -1e30f;
                if (lane == 0) s_sel[r] = bi;
            }
        }
    }
    __syncthreads();

    // ---------------- head ----------------
    float* s_c1   = s_headf;        // [16 o][16 slot]
    float* s_p1   = s_headf + 256;  // [16 o][8]
    float* s_flat = s_headf + 384;  // 128
    float* s_last = s_headf + 512;  // 32
    float* s_outv = s_headf + 544;  // 18

    if (t < 256) {
        int sl = t >> 4, o = t & 15;
        float vv = s_proj[s_sel[sl]*20 + o] + c1b[o];
        s_c1[o*16 + sl] = fmaxf(vv, 0.f);
    }
    __syncthreads();
    if (t < 128) {
        int o = t >> 3, j = t & 7;
        s_p1[o*8 + j] = fmaxf(s_c1[o*16 + 2*j], s_c1[o*16 + 2*j + 1]);
    }
    __syncthreads();
    if (t < 128) {
        int oc = t >> 2, tt = t & 3;
        float a = c2b[oc];
        #pragma unroll
        for (int ic = 0; ic < 16; ic++)
            #pragma unroll
            for (int kk = 0; kk < 5; kk++)
                a += s_p1[ic*8 + tt + kk] * c2w[(oc*16 + ic)*5 + kk];
        s_flat[oc*4 + tt] = fmaxf(a, 0.f);
    }
    __syncthreads();
    if (t < 32) {
        float a = d1b[t];
        #pragma unroll
        for (int i = 0; i < 128; i++) a += s_flat[i] * d1w[t*128 + i];
        a = fmaxf(a, 0.f);
        s_last[t] = a;
        out[2*NG*TOUT + g*32 + t] = a;               // output 2: last
    }
    __syncthreads();
    if (t < TOUT) {
        float a = d2b[t];
        #pragma unroll
        for (int j = 0; j < 32; j++) a += s_last[j] * d2w[t*32 + j];
        s_outv[t] = a;
        out[NG*TOUT + g*TOUT + t] = a;               // output 1: logits
    }
    __syncthreads();
    if (t < TOUT) {
        float m = s_outv[0];
        for (int i = 1; i < TOUT; i++) m = fmaxf(m, s_outv[i]);
        float sum = 0.f;
        for (int i = 0; i < TOUT; i++) sum += expf(s_outv[i] - m);
        out[g*TOUT + t] = s_outv[t] - m - logf(sum); // output 0: log_softmax
    }
}

extern "C" void kernel_launch(void* const* d_in, const int* in_sizes, int n_in,
                              void* d_out, int out_size, void* d_ws, size_t ws_size,
                              hipStream_t stream) {
    (void)in_sizes; (void)n_in; (void)out_size; (void)d_ws; (void)ws_size;
    const float* x   = (const float*)d_in[0];
    const int*   ei  = (const int*)  d_in[1];
    const float* w0  = (const float*)d_in[4];  const float* b0 = (const float*)d_in[5];
    const float* w1  = (const float*)d_in[6];  const float* b1 = (const float*)d_in[7];
    const float* w2  = (const float*)d_in[8];  const float* b2 = (const float*)d_in[9];
    const float* w3  = (const float*)d_in[10]; const float* b3 = (const float*)d_in[11];
    const float* w4  = (const float*)d_in[12]; const float* b4 = (const float*)d_in[13];
    const float* c1w = (const float*)d_in[14]; const float* c1b = (const float*)d_in[15];
    const float* c2w = (const float*)d_in[16]; const float* c2b = (const float*)d_in[17];
    const float* d1w = (const float*)d_in[18]; const float* d1b = (const float*)d_in[19];
    const float* d2w = (const float*)d_in[20]; const float* d2b = (const float*)d_in[21];
    float* out = (float*)d_out;

    dgcnn_fused<<<NG, 512, 0, stream>>>(x, ei,
        w0, b0, w1, b1, w2, b2, w3, b3, w4, b4,
        c1w, c1b, c2w, c2b, d1w, d1b, d2w, d2b, out);
}

// Round 10
// 174.409 us; speedup vs baseline: 4.5306x; 4.5306x over previous
//
#include <hip/hip_runtime.h>
#include <math.h>

#define NPG  256
#define EPG  4096
#define NG   512
#define FIN  128
#define HD   64
#define TOUT 18
#define KTOP 16
#define STB  260              // B-layout [ch][node] stride
#define STA  68               // A-layout [node][ch] stride
#define SRCL_CAP (EPG + 3*NPG)
#define E_TOT (NG*EPG)

// skewed row base for the transposed buffer: shifts each 4-row group by 16B
// -> agg's b32 transposed writes go from 8-way bank conflict to 2-way (free),
//    reads stay contiguous/aligned and lane->node mapping is unchanged.
__device__ __forceinline__ int HB(int k) { return k*STB + (((k>>2)&7)<<2); }

__launch_bounds__(1024)
__global__ void dgcnn_fused(
    const float* __restrict__ x,
    const int*   __restrict__ ei,
    const float* __restrict__ w0, const float* __restrict__ b0,
    const float* __restrict__ w1, const float* __restrict__ b1,
    const float* __restrict__ w2, const float* __restrict__ b2,
    const float* __restrict__ w3, const float* __restrict__ b3,
    const float* __restrict__ w4, const float* __restrict__ b4,
    const float* __restrict__ c1w, const float* __restrict__ c1b,
    const float* __restrict__ c2w, const float* __restrict__ c2b,
    const float* __restrict__ d1w, const float* __restrict__ d1b,
    const float* __restrict__ d2w, const float* __restrict__ d2b,
    float* __restrict__ out)
{
    __shared__ float s_hB[HD*STB + 32];            // h (post-tanh), transposed + skew pad
    __shared__ float s_hl[NPG*STA];                // h_lin [node][ch^xor]; later proj [n][16]
    __shared__ unsigned char s_srcl[SRCL_CAP] __attribute__((aligned(4)));
    __shared__ int   s_off[NPG+1];
    __shared__ int   s_cnt[NPG];
    __shared__ int   s_outd[NPG];
    __shared__ int   s_cur[NPG];
    __shared__ float s_invdeg[NPG];
    __shared__ float s_lin5[NPG];
    __shared__ float s_h5[NPG];
    __shared__ int   s_sel[KTOP];
    __shared__ float s_head[592];

    const int g = blockIdx.x;
    const int t = threadIdx.x;
    const int lane = t & 63;
    const int wid  = t >> 6;
    const int l4 = lane * 4;
    const int gbase = g * NPG;
    const int* __restrict__ srcg = ei + (size_t)g * EPG;
    const int* __restrict__ dstg = ei + (size_t)E_TOT + (size_t)g * EPG;

    // ---------------- phase 0: degrees + 4-padded CSR by dst ----------------
    if (t < NPG) { s_cnt[t] = 0; s_outd[t] = 0; }
    __syncthreads();
    for (int e = t; e < EPG; e += 1024) {
        int s = srcg[e] - gbase, d = dstg[e] - gbase;
        atomicAdd(&s_outd[s], 1);
        atomicAdd(&s_cnt[d], 1);
    }
    __syncthreads();
    if (t < NPG) s_invdeg[t] = 1.0f / (float)(s_outd[t] + 1);
    if (wid == 0) {   // wave-parallel prefix sum of padded counts
        int c0 = s_cnt[l4], c1 = s_cnt[l4+1], c2 = s_cnt[l4+2], c3 = s_cnt[l4+3];
        int p0 = (c0+3)&~3, p1 = (c1+3)&~3, p2 = (c2+3)&~3, p3 = (c3+3)&~3;
        int tot = p0+p1+p2+p3;
        int run = tot;
        #pragma unroll
        for (int o = 1; o < 64; o <<= 1) {
            int v = __shfl_up(run, o);
            if (lane >= o) run += v;
        }
        int base = run - tot;
        s_off[l4]   = base;
        s_off[l4+1] = base + p0;
        s_off[l4+2] = base + p0 + p1;
        s_off[l4+3] = base + p0 + p1 + p2;
        if (lane == 63) s_off[NPG] = run;
    }
    __syncthreads();
    if (t < NPG) s_cur[t] = s_off[t];
    __syncthreads();
    for (int e = t; e < EPG; e += 1024) {
        int s = srcg[e] - gbase, d = dstg[e] - gbase;
        int pos = atomicAdd(&s_cur[d], 1);
        s_srcl[pos] = (unsigned char)s;
    }
    __syncthreads();
    if (t < NPG) {   // pad each list to x4 with sentinel src=d (corrected via 1-npad)
        int pe = s_off[t+1];
        for (int p = s_cur[t]; p < pe; p++) s_srcl[p] = (unsigned char)t;
    }
    __syncthreads();

    float projacc[4][4];
    #pragma unroll
    for (int i = 0; i < 4; i++)
        #pragma unroll
        for (int j = 0; j < 4; j++) projacc[i][j] = 0.f;

    // agg: h[d][c] = tanh(invdeg*(sum_src hl[src][c] + hl[d][c])), 4 dst/wave
    auto aggregate = [&]() {
        const int js = lane >> 4;
        const int q4 = (lane & 15) * 4;
        for (int job = wid; job < 64; job += 16) {
            int d   = job*4 + js;
            int off = s_off[d], pe = s_off[d+1];
            int npad = (pe - off) - s_cnt[d];
            float4 a = *(const float4*)&s_hl[d*STA + (q4 ^ (((d>>2)&7)<<2))];
            float cf = (float)(1 - npad);
            a.x *= cf; a.y *= cf; a.z *= cf; a.w *= cf;
            for (int e = off; e < pe; e += 4) {
                unsigned int sq = *(const unsigned int*)&s_srcl[e];
                #pragma unroll
                for (int m = 0; m < 4; m++) {
                    int src = (sq >> (8*m)) & 255;
                    float4 hv = *(const float4*)&s_hl[src*STA + (q4 ^ (((src>>2)&7)<<2))];
                    a.x += hv.x; a.y += hv.y; a.z += hv.z; a.w += hv.w;
                }
            }
            float id = s_invdeg[d];
            s_hB[HB(q4+0) + d] = tanhf(a.x * id);
            s_hB[HB(q4+1) + d] = tanhf(a.y * id);
            s_hB[HB(q4+2) + d] = tanhf(a.z * id);
            s_hB[HB(q4+3) + d] = tanhf(a.w * id);
        }
    };

    // matmul: h_lin[n][c] = sum_k h[k][n]*w[c][k] + b[c]; wave=ch-quad, lane=4 nodes
    auto matmul64 = [&](const float* __restrict__ w, const float* __restrict__ b) {
        const int c0 = __builtin_amdgcn_readfirstlane(wid * 4);
        const float* wp = w + c0 * HD;
        float acc[4][4];
        #pragma unroll
        for (int i = 0; i < 4; i++)
            #pragma unroll
            for (int j = 0; j < 4; j++) acc[i][j] = 0.f;
        #pragma unroll 8
        for (int k = 0; k < HD; k++) {
            float4 xv = *(const float4*)&s_hB[HB(k) + l4];
            float wv0 = wp[k], wv1 = wp[HD+k], wv2 = wp[2*HD+k], wv3 = wp[3*HD+k];
            float xa[4] = {xv.x, xv.y, xv.z, xv.w};
            #pragma unroll
            for (int i = 0; i < 4; i++) {
                acc[i][0] += xa[i]*wv0; acc[i][1] += xa[i]*wv1;
                acc[i][2] += xa[i]*wv2; acc[i][3] += xa[i]*wv3;
            }
        }
        float4 bb = *(const float4*)&b[c0];
        float ba[4] = {bb.x, bb.y, bb.z, bb.w};
        int colb = (wid*4) ^ ((lane & 7) << 2);   // XOR swizzle vs 16-way write conflict
        #pragma unroll
        for (int i = 0; i < 4; i++) {
            float4 v;
            v.x = acc[i][0]+ba[0]; v.y = acc[i][1]+ba[1];
            v.z = acc[i][2]+ba[2]; v.w = acc[i][3]+ba[3];
            *(float4*)&s_hl[(l4+i)*STA + colb] = v;
        }
    };

    // conv1 projection accumulation (waves 0-3 only), 16 outputs
    auto projpass = [&](int Loff) {
        const int o0 = __builtin_amdgcn_readfirstlane(wid * 4);
        const float* p = c1w + o0*257 + Loff;
        #pragma unroll 8
        for (int k = 0; k < HD; k++) {
            float4 xv = *(const float4*)&s_hB[HB(k) + l4];
            float p0 = p[k], p1 = p[257+k], p2 = p[514+k], p3 = p[771+k];
            float xa[4] = {xv.x, xv.y, xv.z, xv.w};
            #pragma unroll
            for (int i = 0; i < 4; i++) {
                projacc[i][0] += xa[i]*p0; projacc[i][1] += xa[i]*p1;
                projacc[i][2] += xa[i]*p2; projacc[i][3] += xa[i]*p3;
            }
        }
    };

    // ---------------- layer 0 (F=128, x^T staged in 2 chunks) ----------------
    {
        const int c0 = __builtin_amdgcn_readfirstlane(wid * 4);
        float acc[4][4];
        #pragma unroll
        for (int i = 0; i < 4; i++)
            #pragma unroll
            for (int j = 0; j < 4; j++) acc[i][j] = 0.f;
        for (int c2 = 0; c2 < 2; c2++) {
            {   // stage x^T chunk into s_hB
                int kk = (t & 15) * 4, nb = t >> 4;
                #pragma unroll
                for (int r = 0; r < 4; r++) {
                    int nn = nb + r*64;
                    float4 v = *(const float4*)&x[(size_t)(gbase+nn)*FIN + c2*64 + kk];
                    s_hB[HB(kk+0) + nn] = v.x;
                    s_hB[HB(kk+1) + nn] = v.y;
                    s_hB[HB(kk+2) + nn] = v.z;
                    s_hB[HB(kk+3) + nn] = v.w;
                }
            }
            __syncthreads();
            const float* wp = w0 + c0*FIN + c2*64;
            #pragma unroll 8
            for (int k = 0; k < 64; k++) {
                float4 xv = *(const float4*)&s_hB[HB(k) + l4];
                float wv0 = wp[k], wv1 = wp[FIN+k], wv2 = wp[2*FIN+k], wv3 = wp[3*FIN+k];
                float xa[4] = {xv.x, xv.y, xv.z, xv.w};
                #pragma unroll
                for (int i = 0; i < 4; i++) {
                    acc[i][0] += xa[i]*wv0; acc[i][1] += xa[i]*wv1;
                    acc[i][2] += xa[i]*wv2; acc[i][3] += xa[i]*wv3;
                }
            }
            __syncthreads();
        }
        float4 bb = *(const float4*)&b0[c0];
        float ba[4] = {bb.x, bb.y, bb.z, bb.w};
        int colb = (wid*4) ^ ((lane & 7) << 2);
        #pragma unroll
        for (int i = 0; i < 4; i++) {
            float4 v;
            v.x = acc[i][0]+ba[0]; v.y = acc[i][1]+ba[1];
            v.z = acc[i][2]+ba[2]; v.w = acc[i][3]+ba[3];
            *(float4*)&s_hl[(l4+i)*STA + colb] = v;
        }
    }
    __syncthreads();
    aggregate();                       // -> h0
    __syncthreads();

    // ---------------- layers 1..3 (proj of previous layer overlapped) -------
    if (wid < 4) projpass(0);
    matmul64(w1, b1);
    __syncthreads();
    aggregate();                       // -> h1
    __syncthreads();

    if (wid < 4) projpass(64);
    matmul64(w2, b2);
    __syncthreads();
    aggregate();                       // -> h2
    __syncthreads();

    if (wid < 4) projpass(128);
    matmul64(w3, b3);
    __syncthreads();
    aggregate();                       // -> h3
    __syncthreads();

    // ---------------- layer 4 (64->1) + proj3 ----------------
    if (wid < 4) {
        projpass(192);
    } else if (wid < 8) {
        int n = t - 256;
        float a = b4[0];
        #pragma unroll 8
        for (int k = 0; k < HD; k++) a += s_hB[HB(k) + n] * w4[k];
        s_lin5[n] = a;
    }
    __syncthreads();
    if (t < NPG) {
        int d = t;
        int off = s_off[d], pe = s_off[d+1];
        int npad = (pe - off) - s_cnt[d];
        float a = (float)(1 - npad) * s_lin5[d];
        for (int e = off; e < pe; e += 4) {
            unsigned int sq = *(const unsigned int*)&s_srcl[e];
            a += s_lin5[sq & 255] + s_lin5[(sq>>8)&255]
               + s_lin5[(sq>>16)&255] + s_lin5[(sq>>24)&255];
        }
        s_h5[d] = tanhf(a * s_invdeg[d]);
    }
    __syncthreads();
    // h5 proj contribution + store proj rows [n][16] into s_hl; topk
    if (wid < 4) {
        const int o0 = __builtin_amdgcn_readfirstlane(wid * 4);
        float cw0 = c1w[(o0+0)*257 + 256];
        float cw1 = c1w[(o0+1)*257 + 256];
        float cw2 = c1w[(o0+2)*257 + 256];
        float cw3 = c1w[(o0+3)*257 + 256];
        #pragma unroll
        for (int i = 0; i < 4; i++) {
            float hv = s_h5[l4+i];
            float4 v;
            v.x = projacc[i][0] + hv*cw0;
            v.y = projacc[i][1] + hv*cw1;
            v.z = projacc[i][2] + hv*cw2;
            v.w = projacc[i][3] + hv*cw3;
            *(float4*)&s_hl[(l4+i)*16 + wid*4] = v;
        }
    }
    if (wid == 0) {   // top-16: desc value, asc index ties
        float v[4]; int idx[4];
        #pragma unroll
        for (int j = 0; j < 4; j++) { idx[j] = l4+j; v[j] = s_h5[l4+j]; }
        for (int r = 0; r < KTOP; r++) {
            float bv = v[0]; int bi = idx[0];
            #pragma unroll
            for (int j = 1; j < 4; j++)
                if (v[j] > bv || (v[j] == bv && idx[j] < bi)) { bv = v[j]; bi = idx[j]; }
            #pragma unroll
            for (int o = 32; o > 0; o >>= 1) {
                float ov = __shfl_xor(bv, o);
                int   oi = __shfl_xor(bi, o);
                if (ov > bv || (ov == bv && oi < bi)) { bv = ov; bi = oi; }
            }
            if ((bi >> 2) == lane) v[bi & 3] = -1e30f;
            if (lane == 0) s_sel[r] = bi;
        }
    }
    __syncthreads();

    // ---------------- head ----------------
    float* s_c1   = s_head;        // [16 o][16 l]
    float* s_p1   = s_head + 256;  // [16 o][8 j]
    float* s_flat = s_head + 384;  // 128
    float* s_last = s_head + 512;  // 32
    float* s_outv = s_head + 544;  // 18

    if (t < 256) {
        int sl = t >> 4, o = t & 15;
        float vv = s_hl[s_sel[sl]*16 + o] + c1b[o];
        s_c1[o*16 + sl] = fmaxf(vv, 0.f);
    }
    __syncthreads();
    if (t < 128) {
        int o = t >> 3, j = t & 7;
        s_p1[o*8 + j] = fmaxf(s_c1[o*16 + 2*j], s_c1[o*16 + 2*j + 1]);
    }
    __syncthreads();
    if (t < 128) {
        int oc = t >> 2, tt = t & 3;
        float a = c2b[oc];
        #pragma unroll
        for (int ic = 0; ic < 16; ic++)
            #pragma unroll
            for (int kk = 0; kk < 5; kk++)
                a += s_p1[ic*8 + tt + kk] * c2w[(oc*16 + ic)*5 + kk];
        s_flat[oc*4 + tt] = fmaxf(a, 0.f);
    }
    __syncthreads();
    if (t < 32) {
        float a = d1b[t];
        #pragma unroll 16
        for (int i = 0; i < 128; i++) a += s_flat[i] * d1w[t*128 + i];
        a = fmaxf(a, 0.f);
        s_last[t] = a;
        out[2*NG*TOUT + g*32 + t] = a;                 // output 2: last
    }
    __syncthreads();
    if (t < TOUT) {
        float a = d2b[t];
        #pragma unroll
        for (int j = 0; j < 32; j++) a += s_last[j] * d2w[t*32 + j];
        s_outv[t] = a;
        out[NG*TOUT + g*TOUT + t] = a;                 // output 1: logits
    }
    __syncthreads();
    if (t < TOUT) {
        float m = s_outv[0];
        for (int i = 1; i < TOUT; i++) m = fmaxf(m, s_outv[i]);
        float sum = 0.f;
        for (int i = 0; i < TOUT; i++) sum += expf(s_outv[i] - m);
        out[g*TOUT + t] = s_outv[t] - m - logf(sum);   // output 0: log_softmax
    }
}

extern "C" void kernel_launch(void* const* d_in, const int* in_sizes, int n_in,
                              void* d_out, int out_size, void* d_ws, size_t ws_size,
                              hipStream_t stream) {
    (void)in_sizes; (void)n_in; (void)out_size; (void)d_ws; (void)ws_size;
    const float* x   = (const float*)d_in[0];
    const int*   ei  = (const int*)  d_in[1];
    const float* w0  = (const float*)d_in[4];  const float* b0 = (const float*)d_in[5];
    const float* w1  = (const float*)d_in[6];  const float* b1 = (const float*)d_in[7];
    const float* w2  = (const float*)d_in[8];  const float* b2 = (const float*)d_in[9];
    const float* w3  = (const float*)d_in[10]; const float* b3 = (const float*)d_in[11];
    const float* w4  = (const float*)d_in[12]; const float* b4 = (const float*)d_in[13];
    const float* c1w = (const float*)d_in[14]; const float* c1b = (const float*)d_in[15];
    const float* c2w = (const float*)d_in[16]; const float* c2b = (const float*)d_in[17];
    const float* d1w = (const float*)d_in[18]; const float* d1b = (const float*)d_in[19];
    const float* d2w = (const float*)d_in[20]; const float* d2b = (const float*)d_in[21];
    float* out = (float*)d_out;

    dgcnn_fused<<<NG, 1024, 0, stream>>>(x, ei,
        w0, b0, w1, b1, w2, b2, w3, b3, w4, b4,
        c1w, c1b, c2w, c2b, d1w, d1b, d2w, d2b, out);
}